// Round 5
// baseline (370.106 us; speedup 1.0000x reference)
//
#include <hip/hip_runtime.h>
#include <hip/hip_fp16.h>

#define RANK 12
#define RES 192
#define NHW (RES * RES)
#define NF 36
#define ODIM 32
#define TEXW 16            // halfs per texel (12 used + 4 pad) -> 32 B
#define NCELL 32768        // 32^3 cells, 5 bits/dim

typedef float f32x4 __attribute__((ext_vector_type(4)));

// ---------------------------------------------------------------------------
// Zero the histogram (in-graph; hipMemsetAsync may not graph-capture reliably)
// ---------------------------------------------------------------------------
__global__ __launch_bounds__(256) void vme_zero(int* __restrict__ cnt) {
    int i = blockIdx.x * 256 + threadIdx.x;
    if (i < NCELL) cnt[i] = 0;
}

// ---------------------------------------------------------------------------
// Pre-pass: planes [R][H][W] f32 -> [3][H][W][16] fp16 (3.54 MB, L2-resident)
// ---------------------------------------------------------------------------
__global__ __launch_bounds__(256) void vme_transpose(const float* __restrict__ a,
                                                     const float* __restrict__ b,
                                                     const float* __restrict__ c,
                                                     _Float16* __restrict__ t) {
    int idx = blockIdx.x * 256 + threadIdx.x;
    if (idx >= 3 * NHW) return;
    int p = idx / NHW;
    int yx = idx - p * NHW;
    const float* src = (p == 0) ? a : (p == 1) ? b : c;
    _Float16* dst = t + (size_t)idx * TEXW;
#pragma unroll
    for (int r = 0; r < RANK; ++r) dst[r] = (_Float16)src[(size_t)r * NHW + yx];
#pragma unroll
    for (int r = RANK; r < TEXW; ++r) dst[r] = (_Float16)0.0f;
}

__device__ __forceinline__ int cell_of(float x, float y, float z) {
    int qx = min(31, max(0, (int)(x * 32.0f)));
    int qy = min(31, max(0, (int)(y * 32.0f)));
    int qz = min(31, max(0, (int)(z * 32.0f)));
    return (qz << 10) | (qy << 5) | qx;   // x contiguous -> plane rows contiguous
}

// ---------------------------------------------------------------------------
// Sort pass 1: histogram of cell ids
// ---------------------------------------------------------------------------
__global__ __launch_bounds__(256) void vme_hist(const float* __restrict__ xyz,
                                                int* __restrict__ counts, int n) {
    int i = blockIdx.x * 256 + threadIdx.x;
    if (i >= n) return;
    float x = xyz[3 * (size_t)i + 0];
    float y = xyz[3 * (size_t)i + 1];
    float z = xyz[3 * (size_t)i + 2];
    atomicAdd(&counts[cell_of(x, y, z)], 1);
}

// ---------------------------------------------------------------------------
// Sort pass 2: exclusive prefix sum over 32768 counts (one 1024-thread block)
// ---------------------------------------------------------------------------
__global__ __launch_bounds__(1024) void vme_scan(const int* __restrict__ counts,
                                                 int* __restrict__ offs) {
    __shared__ int part[1024];
    int t = threadIdx.x;
    int base = t * (NCELL / 1024);
    int local[NCELL / 1024];
    int s = 0;
#pragma unroll
    for (int k = 0; k < NCELL / 1024; ++k) { local[k] = counts[base + k]; s += local[k]; }
    part[t] = s;
    __syncthreads();
    for (int off = 1; off < 1024; off <<= 1) {
        int v = part[t];
        if (t >= off) v += part[t - off];
        __syncthreads();
        part[t] = v;
        __syncthreads();
    }
    int run = part[t] - s;   // exclusive
#pragma unroll
    for (int k = 0; k < NCELL / 1024; ++k) { offs[base + k] = run; run += local[k]; }
}

// ---------------------------------------------------------------------------
// Sort pass 3: scatter {x,y,z,bitcast(idx)} into cell buckets
// ---------------------------------------------------------------------------
__global__ __launch_bounds__(256) void vme_scatter(const float* __restrict__ xyz,
                                                   int* __restrict__ offs,
                                                   f32x4* __restrict__ sorted, int n) {
    int i = blockIdx.x * 256 + threadIdx.x;
    if (i >= n) return;
    float x = xyz[3 * (size_t)i + 0];
    float y = xyz[3 * (size_t)i + 1];
    float z = xyz[3 * (size_t)i + 2];
    int pos = atomicAdd(&offs[cell_of(x, y, z)], 1);
    f32x4 v = {x, y, z, __uint_as_float((unsigned)i)};
    sorted[pos] = v;
}

__device__ __forceinline__ void decode_texel(const _Float16* __restrict__ tex, float* __restrict__ o) {
    union { uint4 v; _Float16 h[8]; } A;
    union { uint2 v; _Float16 h[4]; } B;
    A.v = *(const uint4*)(tex);
    B.v = *(const uint2*)(tex + 8);
#pragma unroll
    for (int r = 0; r < 8; ++r) o[r] = (float)A.h[r];
#pragma unroll
    for (int r = 0; r < 4; ++r) o[8 + r] = (float)B.h[r];
}

__device__ __forceinline__ void vme_compute_point(float px, float py, float pz,
                                                  const _Float16* __restrict__ tp,
                                                  const float* __restrict__ w,
                                                  float* __restrict__ op) {
    float f[NF];
    float us[3] = {px, px, py};
    float vs[3] = {py, pz, pz};
#pragma unroll
    for (int p = 0; p < 3; ++p) {
        float x = us[p] * (float)(RES - 1);
        float y = vs[p] * (float)(RES - 1);
        x = fminf(fmaxf(x, 0.0f), (float)(RES - 1));
        y = fminf(fmaxf(y, 0.0f), (float)(RES - 1));
        int x0 = (int)x;
        int y0 = (int)y;
        int x1 = min(x0 + 1, RES - 1);
        int y1 = min(y0 + 1, RES - 1);
        float wx = x - (float)x0;
        float wy = y - (float)y0;
        float w00 = (1.0f - wx) * (1.0f - wy);
        float w01 = wx * (1.0f - wy);
        float w10 = (1.0f - wx) * wy;
        float w11 = wx * wy;

        const _Float16* base = tp + (size_t)p * NHW * TEXW;
        float d00[RANK], d01[RANK], d10[RANK], d11[RANK];
        decode_texel(base + (size_t)(y0 * RES + x0) * TEXW, d00);
        decode_texel(base + (size_t)(y0 * RES + x1) * TEXW, d01);
        decode_texel(base + (size_t)(y1 * RES + x0) * TEXW, d10);
        decode_texel(base + (size_t)(y1 * RES + x1) * TEXW, d11);
#pragma unroll
        for (int r = 0; r < RANK; ++r)
            f[p * RANK + r] = w00 * d00[r] + w01 * d01[r] + w10 * d10[r] + w11 * d11[r];
    }

    float acc[ODIM];
#pragma unroll
    for (int o = 0; o < ODIM; ++o) {
        float s = 0.0f;
#pragma unroll
        for (int k = 0; k < NF; ++k) s += f[k] * w[o * NF + k];
        acc[o] = s;
    }
#pragma unroll
    for (int q = 0; q < 8; ++q) {
        f32x4 v = {acc[4 * q + 0], acc[4 * q + 1], acc[4 * q + 2], acc[4 * q + 3]};
        *(f32x4*)(op + 4 * q) = v;
    }
}

// ---------------------------------------------------------------------------
// Main kernel (sorted): coalesced point reads, L1-local taps, row write to
// the point's original output slot.
// ---------------------------------------------------------------------------
__global__ __launch_bounds__(256) void vme_main_sorted(const f32x4* __restrict__ sorted,
                                                       const _Float16* __restrict__ tp,
                                                       const float* __restrict__ w,
                                                       float* __restrict__ out, int n) {
    int j = blockIdx.x * 256 + threadIdx.x;
    if (j >= n) return;
    f32x4 s = sorted[j];
    unsigned idx = __float_as_uint(s.w);
    vme_compute_point(s.x, s.y, s.z, tp, w, out + (size_t)idx * ODIM);
}

// Unsorted variant (ws fits planes only)
__global__ __launch_bounds__(256) void vme_main(const float* __restrict__ xyz,
                                                const _Float16* __restrict__ tp,
                                                const float* __restrict__ w,
                                                float* __restrict__ out, int n) {
    int i = blockIdx.x * 256 + threadIdx.x;
    if (i >= n) return;
    float px = xyz[3 * (size_t)i + 0];
    float py = xyz[3 * (size_t)i + 1];
    float pz = xyz[3 * (size_t)i + 2];
    vme_compute_point(px, py, pz, tp, w, out + (size_t)i * ODIM);
}

// Last-resort fallback: sample original planes directly.
__global__ __launch_bounds__(256) void vme_main_fb(const float* __restrict__ xyz,
                                                   const float* __restrict__ pa,
                                                   const float* __restrict__ pb,
                                                   const float* __restrict__ pc,
                                                   const float* __restrict__ w,
                                                   float* __restrict__ out, int n) {
    int i = blockIdx.x * 256 + threadIdx.x;
    if (i >= n) return;
    float px = xyz[3 * (size_t)i + 0];
    float py = xyz[3 * (size_t)i + 1];
    float pz = xyz[3 * (size_t)i + 2];
    float f[NF];
    float us[3] = {px, px, py};
    float vs[3] = {py, pz, pz};
#pragma unroll
    for (int p = 0; p < 3; ++p) {
        float x = us[p] * (float)(RES - 1);
        float y = vs[p] * (float)(RES - 1);
        x = fminf(fmaxf(x, 0.0f), (float)(RES - 1));
        y = fminf(fmaxf(y, 0.0f), (float)(RES - 1));
        int x0 = (int)x, y0 = (int)y;
        int x1 = min(x0 + 1, RES - 1), y1 = min(y0 + 1, RES - 1);
        float wx = x - (float)x0, wy = y - (float)y0;
        float w00 = (1.0f - wx) * (1.0f - wy), w01 = wx * (1.0f - wy);
        float w10 = (1.0f - wx) * wy, w11 = wx * wy;
        const float* base = (p == 0) ? pa : (p == 1) ? pb : pc;
        int i00 = y0 * RES + x0, i01 = y0 * RES + x1;
        int i10 = y1 * RES + x0, i11 = y1 * RES + x1;
#pragma unroll
        for (int r = 0; r < RANK; ++r) {
            const float* pr = base + (size_t)r * NHW;
            f[p * RANK + r] = w00 * pr[i00] + w01 * pr[i01] + w10 * pr[i10] + w11 * pr[i11];
        }
    }
    float acc[ODIM];
#pragma unroll
    for (int o = 0; o < ODIM; ++o) {
        float s = 0.0f;
#pragma unroll
        for (int k = 0; k < NF; ++k) s += f[k] * w[o * NF + k];
        acc[o] = s;
    }
    float4* op = (float4*)(out + (size_t)i * ODIM);
#pragma unroll
    for (int q = 0; q < 8; ++q)
        op[q] = make_float4(acc[4 * q], acc[4 * q + 1], acc[4 * q + 2], acc[4 * q + 3]);
}

extern "C" void kernel_launch(void* const* d_in, const int* in_sizes, int n_in,
                              void* d_out, int out_size, void* d_ws, size_t ws_size,
                              hipStream_t stream) {
    const float* xyz = (const float*)d_in[0];
    const float* xy  = (const float*)d_in[1];
    const float* xz  = (const float*)d_in[2];
    const float* yz  = (const float*)d_in[3];
    const float* wml = (const float*)d_in[4];
    float* out = (float*)d_out;

    int n = in_sizes[0] / 3;
    int nblk = (n + 255) / 256;
    int tblk = (3 * NHW + 255) / 256;

    const size_t TPB   = (size_t)3 * NHW * TEXW * sizeof(_Float16);  // 3,538,944
    const size_t OFF_CNT  = TPB;                                     // 128 KB
    const size_t OFF_OFFS = TPB + (size_t)NCELL * 4;
    const size_t OFF_SORT = TPB + 2 * (size_t)NCELL * 4;
    const size_t WS_SORTED = OFF_SORT + (size_t)n * 16;

    char* ws = (char*)d_ws;

    if (d_ws && ws_size >= WS_SORTED) {
        _Float16* tp   = (_Float16*)(ws);
        int*      cnt  = (int*)(ws + OFF_CNT);
        int*      offs = (int*)(ws + OFF_OFFS);
        f32x4*    srt  = (f32x4*)(ws + OFF_SORT);

        vme_zero<<<(NCELL + 255) / 256, 256, 0, stream>>>(cnt);
        vme_transpose<<<tblk, 256, 0, stream>>>(xy, xz, yz, tp);
        vme_hist<<<nblk, 256, 0, stream>>>(xyz, cnt, n);
        vme_scan<<<1, 1024, 0, stream>>>(cnt, offs);
        vme_scatter<<<nblk, 256, 0, stream>>>(xyz, offs, srt, n);
        vme_main_sorted<<<nblk, 256, 0, stream>>>(srt, tp, wml, out, n);
    } else if (d_ws && ws_size >= TPB) {
        _Float16* tp = (_Float16*)ws;
        vme_transpose<<<tblk, 256, 0, stream>>>(xy, xz, yz, tp);
        vme_main<<<nblk, 256, 0, stream>>>(xyz, tp, wml, out, n);
    } else {
        vme_main_fb<<<nblk, 256, 0, stream>>>(xyz, xy, xz, yz, wml, out, n);
    }
}

// Round 6
// 197.205 us; speedup vs baseline: 1.8768x; 1.8768x over previous
//
#include <hip/hip_runtime.h>
#include <hip/hip_fp16.h>

#define RANK 12
#define RES 192
#define NHW (RES * RES)
#define NF 36
#define ODIM 32
#define TEXW 16            // halfs per texel (12 used + 4 pad) -> 32 B
#define NB 4096            // 16^3 cells, 4 bits/dim
#define SORTB 256          // sort blocks
#define SORTT 1024         // threads per sort block

typedef float f32x4 __attribute__((ext_vector_type(4)));

// ---------------------------------------------------------------------------
// Pre-pass: planes [R][H][W] f32 -> [3][H][W][16] fp16 (3.54 MB, L2-resident)
// ---------------------------------------------------------------------------
__global__ __launch_bounds__(256) void vme_transpose(const float* __restrict__ a,
                                                     const float* __restrict__ b,
                                                     const float* __restrict__ c,
                                                     _Float16* __restrict__ t) {
    int idx = blockIdx.x * 256 + threadIdx.x;
    if (idx >= 3 * NHW) return;
    int p = idx / NHW;
    int yx = idx - p * NHW;
    const float* src = (p == 0) ? a : (p == 1) ? b : c;
    _Float16* dst = t + (size_t)idx * TEXW;
#pragma unroll
    for (int r = 0; r < RANK; ++r) dst[r] = (_Float16)src[(size_t)r * NHW + yx];
#pragma unroll
    for (int r = RANK; r < TEXW; ++r) dst[r] = (_Float16)0.0f;
}

__device__ __forceinline__ int cell16(float x, float y, float z) {
    int qx = min(15, max(0, (int)(x * 16.0f)));
    int qy = min(15, max(0, (int)(y * 16.0f)));
    int qz = min(15, max(0, (int)(z * 16.0f)));
    return (qz << 8) | (qy << 4) | qx;   // x contiguous -> plane rows contiguous
}

// ---------------------------------------------------------------------------
// S1: per-block LDS histogram -> blkhist[bin*SORTB + blk]
// ---------------------------------------------------------------------------
__global__ __launch_bounds__(SORTT) void vme_hist(const float* __restrict__ xyz,
                                                  int* __restrict__ blkhist, int n) {
    __shared__ int h[NB];
    int t = threadIdx.x, b = blockIdx.x;
    for (int k = t; k < NB; k += SORTT) h[k] = 0;
    __syncthreads();
    int P = (n + SORTB - 1) / SORTB;
    int lo = b * P, hi = min(n, lo + P);
    for (int i = lo + t; i < hi; i += SORTT) {
        float x = xyz[3 * (size_t)i + 0];
        float y = xyz[3 * (size_t)i + 1];
        float z = xyz[3 * (size_t)i + 2];
        atomicAdd(&h[cell16(x, y, z)], 1);
    }
    __syncthreads();
    for (int k = t; k < NB; k += SORTT) blkhist[(size_t)k * SORTB + b] = h[k];
}

// ---------------------------------------------------------------------------
// S2: exclusive scan of NB*SORTB = 1,048,576 ints (3 kernels, in place)
// ---------------------------------------------------------------------------
__global__ __launch_bounds__(1024) void vme_scan1(int* __restrict__ data,
                                                  int* __restrict__ partials) {
    __shared__ int sh[1024];
    int t = threadIdx.x;
    size_t base = (size_t)blockIdx.x * 1024;
    int v = data[base + t];
    sh[t] = v;
    __syncthreads();
    for (int off = 1; off < 1024; off <<= 1) {
        int u = sh[t];
        int add = (t >= off) ? sh[t - off] : 0;
        __syncthreads();
        sh[t] = u + add;
        __syncthreads();
    }
    data[base + t] = sh[t] - v;                 // exclusive
    if (t == 1023) partials[blockIdx.x] = sh[t]; // block total
}

__global__ __launch_bounds__(1024) void vme_scan2(int* __restrict__ partials) {
    __shared__ int sh[1024];
    int t = threadIdx.x;
    int v = partials[t];
    sh[t] = v;
    __syncthreads();
    for (int off = 1; off < 1024; off <<= 1) {
        int u = sh[t];
        int add = (t >= off) ? sh[t - off] : 0;
        __syncthreads();
        sh[t] = u + add;
        __syncthreads();
    }
    partials[t] = sh[t] - v;                    // exclusive
}

__global__ __launch_bounds__(1024) void vme_scan3(int* __restrict__ data,
                                                  const int* __restrict__ partials) {
    size_t base = (size_t)blockIdx.x * 1024;
    data[base + threadIdx.x] += partials[blockIdx.x];
}

// ---------------------------------------------------------------------------
// S3: scatter via LDS ranks + LDS-cached base column. No global atomics.
// ---------------------------------------------------------------------------
__global__ __launch_bounds__(SORTT) void vme_scatter(const float* __restrict__ xyz,
                                                     const int* __restrict__ scanned,
                                                     f32x4* __restrict__ sorted, int n) {
    __shared__ int bases[NB];
    __shared__ int ranks[NB];
    int t = threadIdx.x, b = blockIdx.x;
    for (int k = t; k < NB; k += SORTT) {
        bases[k] = scanned[(size_t)k * SORTB + b];
        ranks[k] = 0;
    }
    __syncthreads();
    int P = (n + SORTB - 1) / SORTB;
    int lo = b * P, hi = min(n, lo + P);
    for (int i = lo + t; i < hi; i += SORTT) {
        float x = xyz[3 * (size_t)i + 0];
        float y = xyz[3 * (size_t)i + 1];
        float z = xyz[3 * (size_t)i + 2];
        int c = cell16(x, y, z);
        int r = atomicAdd(&ranks[c], 1);
        f32x4 v = {x, y, z, __uint_as_float((unsigned)i)};
        sorted[bases[c] + r] = v;
    }
}

__device__ __forceinline__ void decode_texel(const _Float16* __restrict__ tex, float* __restrict__ o) {
    union { uint4 v; _Float16 h[8]; } A;
    union { uint2 v; _Float16 h[4]; } B;
    A.v = *(const uint4*)(tex);
    B.v = *(const uint2*)(tex + 8);
#pragma unroll
    for (int r = 0; r < 8; ++r) o[r] = (float)A.h[r];
#pragma unroll
    for (int r = 0; r < 4; ++r) o[8 + r] = (float)B.h[r];
}

__device__ __forceinline__ void vme_compute_point(float px, float py, float pz,
                                                  const _Float16* __restrict__ tp,
                                                  const float* __restrict__ w,
                                                  float* __restrict__ op) {
    float f[NF];
    float us[3] = {px, px, py};
    float vs[3] = {py, pz, pz};
#pragma unroll
    for (int p = 0; p < 3; ++p) {
        float x = us[p] * (float)(RES - 1);
        float y = vs[p] * (float)(RES - 1);
        x = fminf(fmaxf(x, 0.0f), (float)(RES - 1));
        y = fminf(fmaxf(y, 0.0f), (float)(RES - 1));
        int x0 = (int)x;
        int y0 = (int)y;
        int x1 = min(x0 + 1, RES - 1);
        int y1 = min(y0 + 1, RES - 1);
        float wx = x - (float)x0;
        float wy = y - (float)y0;
        float w00 = (1.0f - wx) * (1.0f - wy);
        float w01 = wx * (1.0f - wy);
        float w10 = (1.0f - wx) * wy;
        float w11 = wx * wy;

        const _Float16* base = tp + (size_t)p * NHW * TEXW;
        float d00[RANK], d01[RANK], d10[RANK], d11[RANK];
        decode_texel(base + (size_t)(y0 * RES + x0) * TEXW, d00);
        decode_texel(base + (size_t)(y0 * RES + x1) * TEXW, d01);
        decode_texel(base + (size_t)(y1 * RES + x0) * TEXW, d10);
        decode_texel(base + (size_t)(y1 * RES + x1) * TEXW, d11);
#pragma unroll
        for (int r = 0; r < RANK; ++r)
            f[p * RANK + r] = w00 * d00[r] + w01 * d01[r] + w10 * d10[r] + w11 * d11[r];
    }

    float acc[ODIM];
#pragma unroll
    for (int o = 0; o < ODIM; ++o) {
        float s = 0.0f;
#pragma unroll
        for (int k = 0; k < NF; ++k) s += f[k] * w[o * NF + k];
        acc[o] = s;
    }
#pragma unroll
    for (int q = 0; q < 8; ++q) {
        f32x4 v = {acc[4 * q + 0], acc[4 * q + 1], acc[4 * q + 2], acc[4 * q + 3]};
        *(f32x4*)(op + 4 * q) = v;
    }
}

// ---------------------------------------------------------------------------
// Main kernel (sorted): coalesced point reads, L1-local taps, row write to
// the point's original output slot.
// ---------------------------------------------------------------------------
__global__ __launch_bounds__(256) void vme_main_sorted(const f32x4* __restrict__ sorted,
                                                       const _Float16* __restrict__ tp,
                                                       const float* __restrict__ w,
                                                       float* __restrict__ out, int n) {
    int j = blockIdx.x * 256 + threadIdx.x;
    if (j >= n) return;
    f32x4 s = sorted[j];
    unsigned idx = __float_as_uint(s.w);
    vme_compute_point(s.x, s.y, s.z, tp, w, out + (size_t)idx * ODIM);
}

// Unsorted variant (ws fits planes only)
__global__ __launch_bounds__(256) void vme_main(const float* __restrict__ xyz,
                                                const _Float16* __restrict__ tp,
                                                const float* __restrict__ w,
                                                float* __restrict__ out, int n) {
    int i = blockIdx.x * 256 + threadIdx.x;
    if (i >= n) return;
    float px = xyz[3 * (size_t)i + 0];
    float py = xyz[3 * (size_t)i + 1];
    float pz = xyz[3 * (size_t)i + 2];
    vme_compute_point(px, py, pz, tp, w, out + (size_t)i * ODIM);
}

// Last-resort fallback: sample original planes directly.
__global__ __launch_bounds__(256) void vme_main_fb(const float* __restrict__ xyz,
                                                   const float* __restrict__ pa,
                                                   const float* __restrict__ pb,
                                                   const float* __restrict__ pc,
                                                   const float* __restrict__ w,
                                                   float* __restrict__ out, int n) {
    int i = blockIdx.x * 256 + threadIdx.x;
    if (i >= n) return;
    float px = xyz[3 * (size_t)i + 0];
    float py = xyz[3 * (size_t)i + 1];
    float pz = xyz[3 * (size_t)i + 2];
    float f[NF];
    float us[3] = {px, px, py};
    float vs[3] = {py, pz, pz};
#pragma unroll
    for (int p = 0; p < 3; ++p) {
        float x = us[p] * (float)(RES - 1);
        float y = vs[p] * (float)(RES - 1);
        x = fminf(fmaxf(x, 0.0f), (float)(RES - 1));
        y = fminf(fmaxf(y, 0.0f), (float)(RES - 1));
        int x0 = (int)x, y0 = (int)y;
        int x1 = min(x0 + 1, RES - 1), y1 = min(y0 + 1, RES - 1);
        float wx = x - (float)x0, wy = y - (float)y0;
        float w00 = (1.0f - wx) * (1.0f - wy), w01 = wx * (1.0f - wy);
        float w10 = (1.0f - wx) * wy, w11 = wx * wy;
        const float* base = (p == 0) ? pa : (p == 1) ? pb : pc;
        int i00 = y0 * RES + x0, i01 = y0 * RES + x1;
        int i10 = y1 * RES + x0, i11 = y1 * RES + x1;
#pragma unroll
        for (int r = 0; r < RANK; ++r) {
            const float* pr = base + (size_t)r * NHW;
            f[p * RANK + r] = w00 * pr[i00] + w01 * pr[i01] + w10 * pr[i10] + w11 * pr[i11];
        }
    }
    float acc[ODIM];
#pragma unroll
    for (int o = 0; o < ODIM; ++o) {
        float s = 0.0f;
#pragma unroll
        for (int k = 0; k < NF; ++k) s += f[k] * w[o * NF + k];
        acc[o] = s;
    }
    float4* op = (float4*)(out + (size_t)i * ODIM);
#pragma unroll
    for (int q = 0; q < 8; ++q)
        op[q] = make_float4(acc[4 * q], acc[4 * q + 1], acc[4 * q + 2], acc[4 * q + 3]);
}

extern "C" void kernel_launch(void* const* d_in, const int* in_sizes, int n_in,
                              void* d_out, int out_size, void* d_ws, size_t ws_size,
                              hipStream_t stream) {
    const float* xyz = (const float*)d_in[0];
    const float* xy  = (const float*)d_in[1];
    const float* xz  = (const float*)d_in[2];
    const float* yz  = (const float*)d_in[3];
    const float* wml = (const float*)d_in[4];
    float* out = (float*)d_out;

    int n = in_sizes[0] / 3;
    int nblk = (n + 255) / 256;
    int tblk = (3 * NHW + 255) / 256;

    const size_t TPB      = (size_t)3 * NHW * TEXW * sizeof(_Float16);  // 3,538,944
    const size_t OFF_HIST = TPB;                                        // 4 MB matrix
    const size_t OFF_PART = OFF_HIST + (size_t)NB * SORTB * 4;
    const size_t OFF_SORT = OFF_PART + 4096;
    const size_t WS_SORTED = OFF_SORT + (size_t)n * 16;

    char* ws = (char*)d_ws;

    if (d_ws && ws_size >= WS_SORTED) {
        _Float16* tp   = (_Float16*)(ws);
        int*      bh   = (int*)(ws + OFF_HIST);
        int*      part = (int*)(ws + OFF_PART);
        f32x4*    srt  = (f32x4*)(ws + OFF_SORT);

        vme_transpose<<<tblk, 256, 0, stream>>>(xy, xz, yz, tp);
        vme_hist<<<SORTB, SORTT, 0, stream>>>(xyz, bh, n);
        vme_scan1<<<(NB * SORTB) / 1024, 1024, 0, stream>>>(bh, part);
        vme_scan2<<<1, 1024, 0, stream>>>(part);
        vme_scan3<<<(NB * SORTB) / 1024, 1024, 0, stream>>>(bh, part);
        vme_scatter<<<SORTB, SORTT, 0, stream>>>(xyz, bh, srt, n);
        vme_main_sorted<<<nblk, 256, 0, stream>>>(srt, tp, wml, out, n);
    } else if (d_ws && ws_size >= TPB) {
        _Float16* tp = (_Float16*)ws;
        vme_transpose<<<tblk, 256, 0, stream>>>(xy, xz, yz, tp);
        vme_main<<<nblk, 256, 0, stream>>>(xyz, tp, wml, out, n);
    } else {
        vme_main_fb<<<nblk, 256, 0, stream>>>(xyz, xy, xz, yz, wml, out, n);
    }
}

// Round 8
// 180.873 us; speedup vs baseline: 2.0462x; 1.0903x over previous
//
#include <hip/hip_runtime.h>
#include <hip/hip_fp16.h>

#define RANK 12
#define RES 192
#define NHW (RES * RES)
#define NF 36
#define ODIM 32
#define TEXW 16            // halfs per texel (12 used + 4 pad) -> 32 B
#define NB 4096            // 16^3 cells, 4 bits/dim
#define SORTB 256          // sort blocks
#define SORTT 1024         // threads per sort block

typedef float f32x4 __attribute__((ext_vector_type(4)));
typedef _Float16 h2 __attribute__((ext_vector_type(2)));

__device__ __forceinline__ float fdot2(h2 a, h2 b, float c) {
#if __has_builtin(__builtin_amdgcn_fdot2)
    return __builtin_amdgcn_fdot2(a, b, c, false);
#else
    return c + (float)a.x * (float)b.x + (float)a.y * (float)b.y;
#endif
}

// ---------------------------------------------------------------------------
// Pre-pass: planes [R][H][W] f32 -> [3][H][W][16] fp16 (3.54 MB, L2-resident)
// + pack w_mlp into half2 words (576 u32) when w2u != nullptr
// ---------------------------------------------------------------------------
__global__ __launch_bounds__(256) void vme_transpose(const float* __restrict__ a,
                                                     const float* __restrict__ b,
                                                     const float* __restrict__ c,
                                                     const float* __restrict__ w,
                                                     _Float16* __restrict__ t,
                                                     unsigned* __restrict__ w2u) {
    int idx = blockIdx.x * 256 + threadIdx.x;
    if (w2u != nullptr && idx < ODIM * NF / 2) {   // 576 packed weight words
        int o = idx / (NF / 2), k = idx - o * (NF / 2);
        union { h2 h; unsigned u; } cv;
        cv.h.x = (_Float16)w[o * NF + 2 * k];
        cv.h.y = (_Float16)w[o * NF + 2 * k + 1];
        w2u[idx] = cv.u;
    }
    if (idx >= 3 * NHW) return;
    int p = idx / NHW;
    int yx = idx - p * NHW;
    const float* src = (p == 0) ? a : (p == 1) ? b : c;
    _Float16* dst = t + (size_t)idx * TEXW;
#pragma unroll
    for (int r = 0; r < RANK; ++r) dst[r] = (_Float16)src[(size_t)r * NHW + yx];
#pragma unroll
    for (int r = RANK; r < TEXW; ++r) dst[r] = (_Float16)0.0f;
}

__device__ __forceinline__ int cell16(float x, float y, float z) {
    int qx = min(15, max(0, (int)(x * 16.0f)));
    int qy = min(15, max(0, (int)(y * 16.0f)));
    int qz = min(15, max(0, (int)(z * 16.0f)));
    return (qz << 8) | (qy << 4) | qx;   // x contiguous -> plane rows contiguous
}

// ---------------------------------------------------------------------------
// S1: per-block LDS histogram -> m[b*NB + k]   (row-contiguous per block)
// ---------------------------------------------------------------------------
__global__ __launch_bounds__(SORTT) void vme_hist(const float* __restrict__ xyz,
                                                  int* __restrict__ m, int n) {
    __shared__ int h[NB];
    int t = threadIdx.x, b = blockIdx.x;
    for (int k = t; k < NB; k += SORTT) h[k] = 0;
    __syncthreads();
    int P = (n + SORTB - 1) / SORTB;
    int lo = b * P, hi = min(n, lo + P);
    for (int i = lo + t; i < hi; i += SORTT) {
        float x = xyz[3 * (size_t)i + 0];
        float y = xyz[3 * (size_t)i + 1];
        float z = xyz[3 * (size_t)i + 2];
        atomicAdd(&h[cell16(x, y, z)], 1);
    }
    __syncthreads();
    for (int k = t; k < NB; k += SORTT) m[(size_t)b * NB + k] = h[k];
}

// ---------------------------------------------------------------------------
// S2a: per-bin exclusive scan over blocks (thread-per-bin; coalesced rows).
// In-place on m; writes per-bin totals T[k].
// ---------------------------------------------------------------------------
__global__ __launch_bounds__(256) void vme_scan_cols(int* __restrict__ m,
                                                     int* __restrict__ T) {
    int k = blockIdx.x * 256 + threadIdx.x;   // 0..NB-1, grid = NB/256
    int run = 0;
#pragma unroll 8
    for (int b = 0; b < SORTB; ++b) {
        size_t p = (size_t)b * NB + k;
        int v = m[p];
        m[p] = run;
        run += v;
    }
    T[k] = run;
}

// ---------------------------------------------------------------------------
// S2b: exclusive scan of the NB bin totals (one block)
// ---------------------------------------------------------------------------
__global__ __launch_bounds__(1024) void vme_scan_bins(int* __restrict__ T) {
    __shared__ int sh[1024];
    int t = threadIdx.x;
    int base = t * (NB / 1024);
    int l[NB / 1024];
    int s = 0;
#pragma unroll
    for (int k = 0; k < NB / 1024; ++k) { l[k] = T[base + k]; s += l[k]; }
    sh[t] = s;
    __syncthreads();
    for (int off = 1; off < 1024; off <<= 1) {
        int u = sh[t];
        int add = (t >= off) ? sh[t - off] : 0;
        __syncthreads();
        sh[t] = u + add;
        __syncthreads();
    }
    int run = sh[t] - s;   // exclusive
#pragma unroll
    for (int k = 0; k < NB / 1024; ++k) { T[base + k] = run; run += l[k]; }
}

// ---------------------------------------------------------------------------
// S3: scatter via LDS ranks; base = m[b*NB+k] + T[k]. No global atomics.
// ---------------------------------------------------------------------------
__global__ __launch_bounds__(SORTT) void vme_scatter(const float* __restrict__ xyz,
                                                     const int* __restrict__ m,
                                                     const int* __restrict__ T,
                                                     f32x4* __restrict__ sorted, int n) {
    __shared__ int bases[NB];
    __shared__ int ranks[NB];
    int t = threadIdx.x, b = blockIdx.x;
    for (int k = t; k < NB; k += SORTT) {
        bases[k] = m[(size_t)b * NB + k] + T[k];
        ranks[k] = 0;
    }
    __syncthreads();
    int P = (n + SORTB - 1) / SORTB;
    int lo = b * P, hi = min(n, lo + P);
    for (int i = lo + t; i < hi; i += SORTT) {
        float x = xyz[3 * (size_t)i + 0];
        float y = xyz[3 * (size_t)i + 1];
        float z = xyz[3 * (size_t)i + 2];
        int c = cell16(x, y, z);
        int r = atomicAdd(&ranks[c], 1);
        f32x4 v = {x, y, z, __uint_as_float((unsigned)i)};
        sorted[bases[c] + r] = v;
    }
}

// ---------------------------------------------------------------------------
// Main kernel (sorted, packed fp16): interp in v_pk_fma_f16, MLP in v_dot2.
// ---------------------------------------------------------------------------
__global__ __launch_bounds__(256) void vme_main_sorted(const f32x4* __restrict__ sorted,
                                                       const _Float16* __restrict__ tp,
                                                       const unsigned* __restrict__ w2u,
                                                       float* __restrict__ out, int n) {
    int j = blockIdx.x * 256 + threadIdx.x;
    if (j >= n) return;
    f32x4 s = sorted[j];
    unsigned idx = __float_as_uint(s.w);
    float px = s.x, py = s.y, pz = s.z;

    h2 f2[NF / 2];
    float us[3] = {px, px, py};
    float vs[3] = {py, pz, pz};

#pragma unroll
    for (int p = 0; p < 3; ++p) {
        float x = us[p] * (float)(RES - 1);
        float y = vs[p] * (float)(RES - 1);
        x = fminf(fmaxf(x, 0.0f), (float)(RES - 1));
        y = fminf(fmaxf(y, 0.0f), (float)(RES - 1));
        int x0 = (int)x;
        int y0 = (int)y;
        int x1 = min(x0 + 1, RES - 1);
        int y1 = min(y0 + 1, RES - 1);
        float wx = x - (float)x0;
        float wy = y - (float)y0;
        _Float16 hw00 = (_Float16)((1.0f - wx) * (1.0f - wy));
        _Float16 hw01 = (_Float16)(wx * (1.0f - wy));
        _Float16 hw10 = (_Float16)((1.0f - wx) * wy);
        _Float16 hw11 = (_Float16)(wx * wy);
        h2 h00 = {hw00, hw00}, h01 = {hw01, hw01}, h10 = {hw10, hw10}, h11 = {hw11, hw11};

        const _Float16* base = tp + (size_t)p * NHW * TEXW;
        const _Float16* t00 = base + (size_t)(y0 * RES + x0) * TEXW;
        const _Float16* t01 = base + (size_t)(y0 * RES + x1) * TEXW;
        const _Float16* t10 = base + (size_t)(y1 * RES + x0) * TEXW;
        const _Float16* t11 = base + (size_t)(y1 * RES + x1) * TEXW;

        union TexA { uint4 v; h2 h[4]; } a00, a01, a10, a11;
        union TexB { uint2 v; h2 h[2]; } b00, b01, b10, b11;
        a00.v = *(const uint4*)(t00);  b00.v = *(const uint2*)(t00 + 8);
        a01.v = *(const uint4*)(t01);  b01.v = *(const uint2*)(t01 + 8);
        a10.v = *(const uint4*)(t10);  b10.v = *(const uint2*)(t10 + 8);
        a11.v = *(const uint4*)(t11);  b11.v = *(const uint2*)(t11 + 8);

#pragma unroll
        for (int q = 0; q < 4; ++q)
            f2[p * 6 + q] = a00.h[q] * h00 + a01.h[q] * h01 + a10.h[q] * h10 + a11.h[q] * h11;
#pragma unroll
        for (int q = 0; q < 2; ++q)
            f2[p * 6 + 4 + q] = b00.h[q] * h00 + b01.h[q] * h01 + b10.h[q] * h10 + b11.h[q] * h11;
    }

    // Dense layer via v_dot2_f32_f16; weights wave-uniform at const offsets.
    float acc[ODIM];
#pragma unroll
    for (int o = 0; o < ODIM; ++o) {
        float sum = 0.0f;
#pragma unroll
        for (int k = 0; k < NF / 2; ++k) {
            union { unsigned u; h2 h; } cv;
            cv.u = w2u[o * (NF / 2) + k];
            sum = fdot2(f2[k], cv.h, sum);
        }
        acc[o] = sum;
    }

    float* op = out + (size_t)idx * ODIM;
#pragma unroll
    for (int q = 0; q < 8; ++q) {
        f32x4 v = {acc[4 * q + 0], acc[4 * q + 1], acc[4 * q + 2], acc[4 * q + 3]};
        *(f32x4*)(op + 4 * q) = v;
    }
}

// ---------------------------------------------------------------------------
// Fallbacks (f32 weights)
// ---------------------------------------------------------------------------
__device__ __forceinline__ void decode_texel(const _Float16* __restrict__ tex, float* __restrict__ o) {
    union { uint4 v; _Float16 h[8]; } A;
    union { uint2 v; _Float16 h[4]; } B;
    A.v = *(const uint4*)(tex);
    B.v = *(const uint2*)(tex + 8);
#pragma unroll
    for (int r = 0; r < 8; ++r) o[r] = (float)A.h[r];
#pragma unroll
    for (int r = 0; r < 4; ++r) o[8 + r] = (float)B.h[r];
}

__device__ __forceinline__ void vme_compute_point(float px, float py, float pz,
                                                  const _Float16* __restrict__ tp,
                                                  const float* __restrict__ w,
                                                  float* __restrict__ op) {
    float f[NF];
    float us[3] = {px, px, py};
    float vs[3] = {py, pz, pz};
#pragma unroll
    for (int p = 0; p < 3; ++p) {
        float x = us[p] * (float)(RES - 1);
        float y = vs[p] * (float)(RES - 1);
        x = fminf(fmaxf(x, 0.0f), (float)(RES - 1));
        y = fminf(fmaxf(y, 0.0f), (float)(RES - 1));
        int x0 = (int)x, y0 = (int)y;
        int x1 = min(x0 + 1, RES - 1), y1 = min(y0 + 1, RES - 1);
        float wx = x - (float)x0, wy = y - (float)y0;
        float w00 = (1.0f - wx) * (1.0f - wy), w01 = wx * (1.0f - wy);
        float w10 = (1.0f - wx) * wy, w11 = wx * wy;
        const _Float16* base = tp + (size_t)p * NHW * TEXW;
        float d00[RANK], d01[RANK], d10[RANK], d11[RANK];
        decode_texel(base + (size_t)(y0 * RES + x0) * TEXW, d00);
        decode_texel(base + (size_t)(y0 * RES + x1) * TEXW, d01);
        decode_texel(base + (size_t)(y1 * RES + x0) * TEXW, d10);
        decode_texel(base + (size_t)(y1 * RES + x1) * TEXW, d11);
#pragma unroll
        for (int r = 0; r < RANK; ++r)
            f[p * RANK + r] = w00 * d00[r] + w01 * d01[r] + w10 * d10[r] + w11 * d11[r];
    }
    float acc[ODIM];
#pragma unroll
    for (int o = 0; o < ODIM; ++o) {
        float s = 0.0f;
#pragma unroll
        for (int k = 0; k < NF; ++k) s += f[k] * w[o * NF + k];
        acc[o] = s;
    }
#pragma unroll
    for (int q = 0; q < 8; ++q) {
        f32x4 v = {acc[4 * q + 0], acc[4 * q + 1], acc[4 * q + 2], acc[4 * q + 3]};
        *(f32x4*)(op + 4 * q) = v;
    }
}

__global__ __launch_bounds__(256) void vme_main(const float* __restrict__ xyz,
                                                const _Float16* __restrict__ tp,
                                                const float* __restrict__ w,
                                                float* __restrict__ out, int n) {
    int i = blockIdx.x * 256 + threadIdx.x;
    if (i >= n) return;
    vme_compute_point(xyz[3 * (size_t)i], xyz[3 * (size_t)i + 1], xyz[3 * (size_t)i + 2],
                      tp, w, out + (size_t)i * ODIM);
}

__global__ __launch_bounds__(256) void vme_main_fb(const float* __restrict__ xyz,
                                                   const float* __restrict__ pa,
                                                   const float* __restrict__ pb,
                                                   const float* __restrict__ pc,
                                                   const float* __restrict__ w,
                                                   float* __restrict__ out, int n) {
    int i = blockIdx.x * 256 + threadIdx.x;
    if (i >= n) return;
    float px = xyz[3 * (size_t)i + 0];
    float py = xyz[3 * (size_t)i + 1];
    float pz = xyz[3 * (size_t)i + 2];
    float f[NF];
    float us[3] = {px, px, py};
    float vs[3] = {py, pz, pz};
#pragma unroll
    for (int p = 0; p < 3; ++p) {
        float x = us[p] * (float)(RES - 1);
        float y = vs[p] * (float)(RES - 1);
        x = fminf(fmaxf(x, 0.0f), (float)(RES - 1));
        y = fminf(fmaxf(y, 0.0f), (float)(RES - 1));
        int x0 = (int)x, y0 = (int)y;
        int x1 = min(x0 + 1, RES - 1), y1 = min(y0 + 1, RES - 1);
        float wx = x - (float)x0, wy = y - (float)y0;
        float w00 = (1.0f - wx) * (1.0f - wy), w01 = wx * (1.0f - wy);
        float w10 = (1.0f - wx) * wy, w11 = wx * wy;
        const float* base = (p == 0) ? pa : (p == 1) ? pb : pc;
        int i00 = y0 * RES + x0, i01 = y0 * RES + x1;
        int i10 = y1 * RES + x0, i11 = y1 * RES + x1;
#pragma unroll
        for (int r = 0; r < RANK; ++r) {
            const float* pr = base + (size_t)r * NHW;
            f[p * RANK + r] = w00 * pr[i00] + w01 * pr[i01] + w10 * pr[i10] + w11 * pr[i11];
        }
    }
    float acc[ODIM];
#pragma unroll
    for (int o = 0; o < ODIM; ++o) {
        float s = 0.0f;
#pragma unroll
        for (int k = 0; k < NF; ++k) s += f[k] * w[o * NF + k];
        acc[o] = s;
    }
    float4* op = (float4*)(out + (size_t)i * ODIM);
#pragma unroll
    for (int q = 0; q < 8; ++q)
        op[q] = make_float4(acc[4 * q], acc[4 * q + 1], acc[4 * q + 2], acc[4 * q + 3]);
}

extern "C" void kernel_launch(void* const* d_in, const int* in_sizes, int n_in,
                              void* d_out, int out_size, void* d_ws, size_t ws_size,
                              hipStream_t stream) {
    const float* xyz = (const float*)d_in[0];
    const float* xy  = (const float*)d_in[1];
    const float* xz  = (const float*)d_in[2];
    const float* yz  = (const float*)d_in[3];
    const float* wml = (const float*)d_in[4];
    float* out = (float*)d_out;

    int n = in_sizes[0] / 3;
    int nblk = (n + 255) / 256;
    int tblk = (3 * NHW + 255) / 256;

    const size_t TPB      = (size_t)3 * NHW * TEXW * sizeof(_Float16);  // 3,538,944
    const size_t OFF_W2   = TPB;                                        // 2304 B (pad 4K)
    const size_t OFF_HIST = TPB + 4096;                                 // 4 MB matrix
    const size_t OFF_T    = OFF_HIST + (size_t)NB * SORTB * 4;          // 16 KB
    const size_t OFF_SORT = OFF_T + (size_t)NB * 4;
    const size_t WS_SORTED = OFF_SORT + (size_t)n * 16;

    char* ws = (char*)d_ws;

    if (d_ws && ws_size >= WS_SORTED) {
        _Float16* tp   = (_Float16*)(ws);
        unsigned* w2u  = (unsigned*)(ws + OFF_W2);
        int*      m    = (int*)(ws + OFF_HIST);
        int*      T    = (int*)(ws + OFF_T);
        f32x4*    srt  = (f32x4*)(ws + OFF_SORT);

        vme_transpose<<<tblk, 256, 0, stream>>>(xy, xz, yz, wml, tp, w2u);
        vme_hist<<<SORTB, SORTT, 0, stream>>>(xyz, m, n);
        vme_scan_cols<<<NB / 256, 256, 0, stream>>>(m, T);
        vme_scan_bins<<<1, 1024, 0, stream>>>(T);
        vme_scatter<<<SORTB, SORTT, 0, stream>>>(xyz, m, T, srt, n);
        vme_main_sorted<<<nblk, 256, 0, stream>>>(srt, tp, w2u, out, n);
    } else if (d_ws && ws_size >= TPB) {
        _Float16* tp = (_Float16*)ws;
        vme_transpose<<<tblk, 256, 0, stream>>>(xy, xz, yz, wml, tp, (unsigned*)nullptr);
        vme_main<<<nblk, 256, 0, stream>>>(xyz, tp, wml, out, n);
    } else {
        vme_main_fb<<<nblk, 256, 0, stream>>>(xyz, xy, xz, yz, wml, out, n);
    }
}